// Round 1
// baseline (80.887 us; speedup 1.0000x reference)
//
#include <hip/hip_runtime.h>

#define NPOS 8500
#define BB 4
#define EMB 32
#define KP 16
#define MOMSTRIDE (KP + KP * EMB) /* 528 floats per batch: S[16] then M[16][32] */
#define NCH 128
#define CHL 67 /* 128*67 = 8576 >= 8500 */
#define TILE 128
#define HALO (TILE + 4) /* 132 staged x positions: [start-2, start+130) */
#define NT ((NPOS + TILE - 1) / TILE) /* 67 */

__global__ void zero_mom(float* __restrict__ mom) {
    int i = blockIdx.x * blockDim.x + threadIdx.x;
    if (i < BB * MOMSTRIDE) mom[i] = 0.0f;
}

// Moments: M[k][e] = sum_j v_j^k * emb[angle_j][e],  S[k] = sum_j v_j^k
// thread = (k,e) pair; each block reduces a 67-element j-chunk; atomicAdd partials.
__global__ __launch_bounds__(512) void moments_kernel(
    const float* __restrict__ inten, const int* __restrict__ angle,
    const float* __restrict__ emb, float* __restrict__ mom) {
    const int b = blockIdx.x / NCH;
    const int chunk = blockIdx.x % NCH;
    const int t = threadIdx.x;
    const int k = t >> 5;
    const int e = t & 31;
    int jlo = chunk * CHL;
    int jhi = jlo + CHL;
    if (jhi > NPOS) jhi = NPOS;
    float acc = 0.0f, sacc = 0.0f;
    for (int j = jlo; j < jhi; ++j) {
        float v = inten[b * NPOS + j] * 0.01f; // uniform load -> s_load
        int a = angle[b * NPOS + j];
        float ev = emb[a * EMB + e]; // one 128B row per 32 lanes, L2-resident
        float v2 = v * v, v4 = v2 * v2, v8 = v4 * v4;
        float p = 1.0f;
        if (k & 1) p *= v;
        if (k & 2) p *= v2;
        if (k & 4) p *= v4;
        if (k & 8) p *= v8;
        acc = fmaf(p, ev, acc);
        sacc += p;
    }
    atomicAdd(&mom[b * MOMSTRIDE + KP + k * EMB + e], acc);
    if (e == 0) atomicAdd(&mom[b * MOMSTRIDE + k], sacc);
}

// Fused: x from moments -> conv1+relu -> conv2 + residual + relu -> out [B,32,N]
__global__ __launch_bounds__(256) void main_kernel(
    const float* __restrict__ inten, const float* __restrict__ mom,
    const float* __restrict__ w1, const float* __restrict__ b1,
    const float* __restrict__ w2, const float* __restrict__ b2,
    float* __restrict__ out) {
    __shared__ float S[KP];
    __shared__ float M[KP * EMB];
    __shared__ float w1t[96 * 32]; // [c*3+d][o]
    __shared__ float w2t[96 * 32];
    __shared__ float b1s[32], b2s[32];
    __shared__ float xs[32 * HALO]; // [e][idx], idx = pos - (start-2)
    __shared__ float hs[32 * HALO];

    const int t = threadIdx.x;
    const int b = blockIdx.x / NT;
    const int tile = blockIdx.x % NT;
    const int start = tile * TILE;

    // ---- load moments + weights into LDS ----
    for (int i = t; i < KP * EMB; i += 256) M[i] = mom[b * MOMSTRIDE + KP + i];
    if (t < KP) S[t] = mom[b * MOMSTRIDE + t];
    for (int i = t; i < 3072; i += 256) {
        int cd = i >> 5, o = i & 31;
        w1t[i] = w1[o * 96 + cd]; // i = cd*32+o
        w2t[i] = w2[o * 96 + cd];
    }
    if (t < 32) { b1s[t] = b1[t]; b2s[t] = b2[t]; }
    __syncthreads();

    // ---- stage x for [start-2, start+130) from rank-16 moments ----
    if (t < HALO) {
        const int idx = t;
        const int pos = start - 2 + idx;
        if (pos >= 0 && pos < NPOS) {
            const float u = inten[b * NPOS + pos] * 0.01f;
            float q[KP];
            q[0] = 1.0f;
#pragma unroll
            for (int k = 1; k < KP; ++k) q[k] = q[k - 1] * u * (1.0f / (float)k);
            float denom = 0.0f;
#pragma unroll
            for (int k = 0; k < KP; ++k) denom = fmaf(q[k], S[k], denom);
            const float rd = 1.0f / denom;
#pragma unroll
            for (int e = 0; e < EMB; ++e) {
                float acc = 0.0f;
#pragma unroll
                for (int k = 0; k < KP; ++k) acc = fmaf(q[k], M[k * EMB + e], acc);
                xs[e * HALO + idx] = acc * rd;
            }
        } else {
#pragma unroll
            for (int e = 0; e < EMB; ++e) xs[e * HALO + idx] = 0.0f;
        }
    }
    __syncthreads();

    const int g = t >> 5;   // output-channel group
    const int lane = t & 31; // position lane

    // ---- conv1 + relu -> hs, for idx in [1, 131) (positions start-1 .. start+129) ----
#pragma unroll
    for (int qq = 0; qq < 5; ++qq) {
        const int i = 1 + lane + 32 * qq;
        if (i < HALO - 1) {
            const int pos = start - 2 + i;
            const bool valid = (pos >= 0) && (pos < NPOS);
            float a0 = b1s[g], a1 = b1s[g + 8], a2 = b1s[g + 16], a3 = b1s[g + 24];
#pragma unroll 8
            for (int c = 0; c < 32; ++c) {
                const float xm = xs[c * HALO + i - 1];
                const float x0 = xs[c * HALO + i];
                const float xp = xs[c * HALO + i + 1];
                const float* wc = &w1t[c * 96];
                a0 = fmaf(wc[g], xm, a0);      a0 = fmaf(wc[32 + g], x0, a0);      a0 = fmaf(wc[64 + g], xp, a0);
                a1 = fmaf(wc[8 + g], xm, a1);  a1 = fmaf(wc[40 + g], x0, a1);      a1 = fmaf(wc[72 + g], xp, a1);
                a2 = fmaf(wc[16 + g], xm, a2); a2 = fmaf(wc[48 + g], x0, a2);      a2 = fmaf(wc[80 + g], xp, a2);
                a3 = fmaf(wc[24 + g], xm, a3); a3 = fmaf(wc[56 + g], x0, a3);      a3 = fmaf(wc[88 + g], xp, a3);
            }
            hs[g * HALO + i] = valid ? fmaxf(a0, 0.0f) : 0.0f;
            hs[(g + 8) * HALO + i] = valid ? fmaxf(a1, 0.0f) : 0.0f;
            hs[(g + 16) * HALO + i] = valid ? fmaxf(a2, 0.0f) : 0.0f;
            hs[(g + 24) * HALO + i] = valid ? fmaxf(a3, 0.0f) : 0.0f;
        }
    }
    __syncthreads();

    // ---- conv2 + residual + relu -> out, for idx in [2, 130) (positions start .. start+128) ----
#pragma unroll
    for (int qq = 0; qq < 4; ++qq) {
        const int i = 2 + lane + 32 * qq;
        const int p = start + (i - 2);
        if (p < NPOS) {
            float a0 = b2s[g], a1 = b2s[g + 8], a2 = b2s[g + 16], a3 = b2s[g + 24];
#pragma unroll 8
            for (int c = 0; c < 32; ++c) {
                const float hm = hs[c * HALO + i - 1];
                const float h0 = hs[c * HALO + i];
                const float hp = hs[c * HALO + i + 1];
                const float* wc = &w2t[c * 96];
                a0 = fmaf(wc[g], hm, a0);      a0 = fmaf(wc[32 + g], h0, a0);      a0 = fmaf(wc[64 + g], hp, a0);
                a1 = fmaf(wc[8 + g], hm, a1);  a1 = fmaf(wc[40 + g], h0, a1);      a1 = fmaf(wc[72 + g], hp, a1);
                a2 = fmaf(wc[16 + g], hm, a2); a2 = fmaf(wc[48 + g], h0, a2);      a2 = fmaf(wc[80 + g], hp, a2);
                a3 = fmaf(wc[24 + g], hm, a3); a3 = fmaf(wc[56 + g], h0, a3);      a3 = fmaf(wc[88 + g], hp, a3);
            }
            out[(size_t)(b * 32 + g) * NPOS + p] = fmaxf(xs[g * HALO + i] + a0, 0.0f);
            out[(size_t)(b * 32 + g + 8) * NPOS + p] = fmaxf(xs[(g + 8) * HALO + i] + a1, 0.0f);
            out[(size_t)(b * 32 + g + 16) * NPOS + p] = fmaxf(xs[(g + 16) * HALO + i] + a2, 0.0f);
            out[(size_t)(b * 32 + g + 24) * NPOS + p] = fmaxf(xs[(g + 24) * HALO + i] + a3, 0.0f);
        }
    }
}

extern "C" void kernel_launch(void* const* d_in, const int* in_sizes, int n_in,
                              void* d_out, int out_size, void* d_ws, size_t ws_size,
                              hipStream_t stream) {
    const float* inten = (const float*)d_in[0];
    const int* angle = (const int*)d_in[1];
    const float* emb = (const float*)d_in[2];
    const float* w1 = (const float*)d_in[3];
    const float* b1 = (const float*)d_in[4];
    const float* w2 = (const float*)d_in[5];
    const float* b2 = (const float*)d_in[6];
    float* out = (float*)d_out;
    float* mom = (float*)d_ws; // BB*528 floats = 8448 B

    zero_mom<<<(BB * MOMSTRIDE + 255) / 256, 256, 0, stream>>>(mom);
    moments_kernel<<<BB * NCH, 512, 0, stream>>>(inten, angle, emb, mom);
    main_kernel<<<BB * NT, 256, 0, stream>>>(inten, mom, w1, b1, w2, b2, out);
}

// Round 2
// 39.768 us; speedup vs baseline: 2.0340x; 2.0340x over previous
//
#include <hip/hip_runtime.h>

#define NPOS 8500
#define BB 4
#define EMB 32
#define KP 16
#define MOM 528            /* S[16] + M[16][32] per batch */
#define TOUT 62            /* output positions per tile */
#define STG 68             /* staged x positions: [start-2, start+66) */
#define STR 72             /* LDS row stride (floats), 288B = 16B-aligned */
#define NT 138             /* ceil(8500/62) */

// ---------------- stage 1: per-block partial moments (deterministic) ----------------
// M[k][e] = sum_j v_j^k * emb[angle_j][e],  S[k] = sum_j v_j^k,  v = inten/100
__global__ __launch_bounds__(256) void moments_partial(
    const float* __restrict__ inten, const int* __restrict__ angle,
    const float* __restrict__ emb, float* __restrict__ part,
    int nblk, int jpb, int jps)
{
    const int b = blockIdx.x / nblk;
    const int blk = blockIdx.x % nblk;
    const int t = threadIdx.x;
    const int sub = t >> 5;   // 8 j-subchunks
    const int e = t & 31;     // embed lane
    const int jlo = blk * jpb;
    const int jhi = min(jlo + jpb, NPOS);
    const int js = jlo + sub * jps;
    const int je = min(js + jps, jhi);

    float accM[KP], accS[KP];
#pragma unroll
    for (int k = 0; k < KP; ++k) { accM[k] = 0.f; accS[k] = 0.f; }

    const float* ib = inten + b * NPOS;
    const int* ab = angle + b * NPOS;
    for (int j = js; j < je; ++j) {
        const float v = ib[j] * 0.01f;
        const int a = ab[j];
        const float ev = emb[a * EMB + e];   // one 128B row per 32-lane group
        float p = 1.0f;
        accM[0] += ev;
        accS[0] += 1.0f;
#pragma unroll
        for (int k = 1; k < KP; ++k) {
            p *= v;
            accM[k] = fmaf(p, ev, accM[k]);
            accS[k] += p;
        }
    }

    __shared__ float red[8][MOM];
#pragma unroll
    for (int k = 0; k < KP; ++k) red[sub][KP + k * EMB + e] = accM[k];
    if (e == 0) {
#pragma unroll
        for (int k = 0; k < KP; ++k) red[sub][k] = accS[k];
    }
    __syncthreads();
    for (int i = t; i < MOM; i += 256) {
        float s = 0.f;
#pragma unroll
        for (int u = 0; u < 8; ++u) s += red[u][i];
        part[(size_t)(b * nblk + blk) * MOM + i] = s;
    }
}

// ---------------- stage 2: fixed-order reduce (+ one block transposes weights) ----------------
__global__ __launch_bounds__(512) void moments_reduce(
    const float* __restrict__ part, float* __restrict__ mom, int nblk,
    const float* __restrict__ w1, const float* __restrict__ w2,
    float* __restrict__ wt)
{
    const int b = blockIdx.x;
    if (b < BB) {
        for (int i = threadIdx.x; i < MOM; i += 512) {
            float s = 0.f;
#pragma unroll 8
            for (int u = 0; u < nblk; ++u) s += part[(size_t)(b * nblk + u) * MOM + i];
            mom[b * MOM + i] = s;
        }
    } else {
        // transpose [o][c*3+d] -> [c*3+d][o] once, so main_kernel stages linearly
        for (int i = threadIdx.x; i < 3072; i += 512) {
            const int o = i / 96, cd = i % 96;
            wt[cd * 32 + o] = w1[i];
            wt[3072 + cd * 32 + o] = w2[i];
        }
    }
}

// ---------------- stage 3: fused x-from-moments -> conv1+relu -> conv2+res+relu ----------------
__global__ __launch_bounds__(256) void main_kernel(
    const float* __restrict__ inten, const float* __restrict__ mom,
    const float* __restrict__ wt, const float* __restrict__ b1,
    const float* __restrict__ b2, float* __restrict__ out)
{
    __shared__ float w1t[3072];      // [c*3+d][o]
    __shared__ float w2t[3072];
    __shared__ float Ms[KP * EMB];   // [k][e]
    __shared__ float Ss[KP];
    __shared__ float b1s[EMB], b2s[EMB];
    __shared__ float qs[STG][KP + 1]; // padded: conflict-free writes
    __shared__ float xs[EMB][STR];
    __shared__ float hs[EMB][STR];

    const int t = threadIdx.x;
    const int b = blockIdx.x / NT;
    const int tile = blockIdx.x % NT;
    const int start = tile * TOUT;

    // ---- stage LDS: weights (linear), moments, biases ----
    for (int i = t; i < 3072; i += 256) {
        w1t[i] = wt[i];
        w2t[i] = wt[3072 + i];
    }
    for (int i = t; i < KP * EMB; i += 256) Ms[i] = mom[b * MOM + KP + i];
    if (t < KP) Ss[t] = mom[b * MOM + t];
    if (t < EMB) { b1s[t] = b1[t]; b2s[t] = b2[t]; }
    __syncthreads();

    // ---- S1: q-table (q_k = u^k/k! / denom), zero rows for padded positions ----
    if (t < STG) {
        const int pos = start - 2 + t;
        if (pos >= 0 && pos < NPOS) {
            const float u = inten[b * NPOS + pos] * 0.01f;
            float q[KP];
            q[0] = 1.0f;
#pragma unroll
            for (int k = 1; k < KP; ++k) q[k] = q[k - 1] * u * (1.0f / (float)k);
            float denom = 0.f;
#pragma unroll
            for (int k = 0; k < KP; ++k) denom = fmaf(q[k], Ss[k], denom);
            const float rd = 1.0f / denom;
#pragma unroll
            for (int k = 0; k < KP; ++k) qs[t][k] = q[k] * rd;
        } else {
#pragma unroll
            for (int k = 0; k < KP; ++k) qs[t][k] = 0.f;
        }
    }
    __syncthreads();

    // ---- S2: x[e][idx] = sum_k qs[idx][k] * M[k][e] ----
    for (int i = t; i < STG * EMB; i += 256) {
        const int pos = i >> 5, e = i & 31;
        float acc = 0.f;
#pragma unroll
        for (int k = 0; k < KP; ++k) acc = fmaf(qs[pos][k], Ms[k * EMB + e], acc);
        xs[e][pos] = acc;
    }
    __syncthreads();

    const int g = t >> 5;       // 8 channel groups of 4 consecutive channels
    const int lane = t & 31;    // position lane (2 positions each)
    const int o0 = g * 4;

    // ---- C1: conv1 + relu -> hs, h idx in [1,65) ----
    {
        float acc[4][2];
#pragma unroll
        for (int oo = 0; oo < 4; ++oo) { acc[oo][0] = b1s[o0 + oo]; acc[oo][1] = b1s[o0 + oo]; }
        const int i0 = 2 * lane;   // window x[i0..i0+3] -> outputs i0+1, i0+2
#pragma unroll 8
        for (int c = 0; c < 32; ++c) {
            const float* xr = &xs[c][i0];
            const float x0 = xr[0], x1 = xr[1], x2 = xr[2], x3 = xr[3];
            const float4 W0 = *(const float4*)&w1t[(c * 3 + 0) * 32 + o0];
            const float4 W1 = *(const float4*)&w1t[(c * 3 + 1) * 32 + o0];
            const float4 W2 = *(const float4*)&w1t[(c * 3 + 2) * 32 + o0];
            const float wa[4] = {W0.x, W0.y, W0.z, W0.w};
            const float wb[4] = {W1.x, W1.y, W1.z, W1.w};
            const float wc[4] = {W2.x, W2.y, W2.z, W2.w};
#pragma unroll
            for (int oo = 0; oo < 4; ++oo) {
                acc[oo][0] = fmaf(wa[oo], x0, acc[oo][0]);
                acc[oo][0] = fmaf(wb[oo], x1, acc[oo][0]);
                acc[oo][0] = fmaf(wc[oo], x2, acc[oo][0]);
                acc[oo][1] = fmaf(wa[oo], x1, acc[oo][1]);
                acc[oo][1] = fmaf(wb[oo], x2, acc[oo][1]);
                acc[oo][1] = fmaf(wc[oo], x3, acc[oo][1]);
            }
        }
#pragma unroll
        for (int pp = 0; pp < 2; ++pp) {
            const int idx = i0 + 1 + pp;
            const int pos = start - 2 + idx;
            const bool valid = (pos >= 0) && (pos < NPOS);
#pragma unroll
            for (int oo = 0; oo < 4; ++oo)
                hs[o0 + oo][idx] = valid ? fmaxf(acc[oo][pp], 0.f) : 0.f;
        }
    }
    __syncthreads();

    // ---- C2: conv2 + residual + relu -> out, out idx in [2,64) ----
    {
        float acc[4][2];
#pragma unroll
        for (int oo = 0; oo < 4; ++oo) { acc[oo][0] = b2s[o0 + oo]; acc[oo][1] = b2s[o0 + oo]; }
        const int i0 = 2 * lane;   // reads h[i0+1..i0+4] -> outputs idx i0+2, i0+3
#pragma unroll 8
        for (int c = 0; c < 32; ++c) {
            const float* hr = &hs[c][i0 + 1];
            const float h0 = hr[0], h1 = hr[1], h2 = hr[2], h3 = hr[3];
            const float4 W0 = *(const float4*)&w2t[(c * 3 + 0) * 32 + o0];
            const float4 W1 = *(const float4*)&w2t[(c * 3 + 1) * 32 + o0];
            const float4 W2 = *(const float4*)&w2t[(c * 3 + 2) * 32 + o0];
            const float wa[4] = {W0.x, W0.y, W0.z, W0.w};
            const float wb[4] = {W1.x, W1.y, W1.z, W1.w};
            const float wc[4] = {W2.x, W2.y, W2.z, W2.w};
#pragma unroll
            for (int oo = 0; oo < 4; ++oo) {
                acc[oo][0] = fmaf(wa[oo], h0, acc[oo][0]);
                acc[oo][0] = fmaf(wb[oo], h1, acc[oo][0]);
                acc[oo][0] = fmaf(wc[oo], h2, acc[oo][0]);
                acc[oo][1] = fmaf(wa[oo], h1, acc[oo][1]);
                acc[oo][1] = fmaf(wb[oo], h2, acc[oo][1]);
                acc[oo][1] = fmaf(wc[oo], h3, acc[oo][1]);
            }
        }
        if (lane < 31) {                       // idx 2+2*lane(+1) < 64
            const int iA = 2 * lane + 2;
            const int p0 = start + 2 * lane;
#pragma unroll
            for (int oo = 0; oo < 4; ++oo) {
                const float r0 = fmaxf(xs[o0 + oo][iA] + acc[oo][0], 0.f);
                const float r1 = fmaxf(xs[o0 + oo][iA + 1] + acc[oo][1], 0.f);
                const size_t base = (size_t)(b * EMB + o0 + oo) * NPOS + p0;
                if (p0 + 1 < NPOS) {
                    *(float2*)&out[base] = make_float2(r0, r1);
                } else if (p0 < NPOS) {
                    out[base] = r0;
                }
            }
        }
    }
}

extern "C" void kernel_launch(void* const* d_in, const int* in_sizes, int n_in,
                              void* d_out, int out_size, void* d_ws, size_t ws_size,
                              hipStream_t stream) {
    const float* inten = (const float*)d_in[0];
    const int* angle = (const int*)d_in[1];
    const float* emb = (const float*)d_in[2];
    const float* w1 = (const float*)d_in[3];
    const float* b1 = (const float*)d_in[4];
    const float* w2 = (const float*)d_in[5];
    const float* b2 = (const float*)d_in[6];
    float* out = (float*)d_out;

    float* mom = (float*)d_ws;                          // BB*528 floats  = 8448 B
    float* wt = (float*)((char*)d_ws + 8448);           // 6144 floats    = 24576 B
    float* part = (float*)((char*)d_ws + 8448 + 24576); // BB*nblk*528 floats

    int nblk = 128;
    while (nblk > 8 &&
           (size_t)(8448 + 24576) + (size_t)BB * nblk * MOM * 4 > ws_size)
        nblk >>= 1;
    const int jpb = (NPOS + nblk - 1) / nblk;
    const int jps = (jpb + 7) / 8;

    moments_partial<<<BB * nblk, 256, 0, stream>>>(inten, angle, emb, part, nblk, jpb, jps);
    moments_reduce<<<BB + 1, 512, 0, stream>>>(part, mom, nblk, w1, w2, wt);
    main_kernel<<<BB * NT, 256, 0, stream>>>(inten, mom, wt, b1, b2, out);
}

// Round 3
// 37.783 us; speedup vs baseline: 2.1408x; 1.0525x over previous
//
#include <hip/hip_runtime.h>

#define NPOS 8500
#define BB 4
#define EMB 32
#define KP 16
#define MOM 528            /* S[16] + M[16][32] per batch, pre-scaled by 1/k! */
#define TOUT 124           /* output positions per tile */
#define STG 132            /* staged x idx [0,132): pos start-2 .. start+129 */
#define XSTR 132           /* row stride floats: 528B, 16B-aligned */
#define NT 69              /* ceil(8500/124) */

__device__ __constant__ float c_invf[KP] = {
    1.f, 1.f, 0.5f, 1.f/6.f, 1.f/24.f, 1.f/120.f, 1.f/720.f, 1.f/5040.f,
    1.f/40320.f, 1.f/362880.f, 1.f/3628800.f, 1.f/39916800.f,
    1.f/479001600.f, 1.f/6227020800.f, 1.f/87178291200.f, 1.f/1307674368000.f};

// ---------------- stage 1: per-block partial moments (deterministic) ----------------
__global__ __launch_bounds__(256) void moments_partial(
    const float* __restrict__ inten, const int* __restrict__ angle,
    const float* __restrict__ emb, float* __restrict__ part,
    int nblk, int jpb, int jps)
{
    const int b = blockIdx.x / nblk;
    const int blk = blockIdx.x % nblk;
    const int t = threadIdx.x;
    const int sub = t >> 5;
    const int e = t & 31;
    const int jlo = blk * jpb;
    const int jhi = min(jlo + jpb, NPOS);
    const int js = jlo + sub * jps;
    const int je = min(js + jps, jhi);

    float accM[KP], accS[KP];
#pragma unroll
    for (int k = 0; k < KP; ++k) { accM[k] = 0.f; accS[k] = 0.f; }

    const float* ib = inten + b * NPOS;
    const int* ab = angle + b * NPOS;
    for (int j = js; j < je; ++j) {
        const float v = ib[j] * 0.01f;
        const int a = ab[j];
        const float ev = emb[a * EMB + e];
        float p = 1.0f;
        accM[0] += ev;
        accS[0] += 1.0f;
#pragma unroll
        for (int k = 1; k < KP; ++k) {
            p *= v;
            accM[k] = fmaf(p, ev, accM[k]);
            accS[k] += p;
        }
    }

    __shared__ float red[8][MOM];
#pragma unroll
    for (int k = 0; k < KP; ++k) red[sub][KP + k * EMB + e] = accM[k];
    if (e == 0) {
#pragma unroll
        for (int k = 0; k < KP; ++k) red[sub][k] = accS[k];
    }
    __syncthreads();
    for (int i = t; i < MOM; i += 256) {
        float s = 0.f;
#pragma unroll
        for (int u = 0; u < 8; ++u) s += red[u][i];
        part[(size_t)(b * nblk + blk) * MOM + i] = s;
    }
}

// ---------------- stage 2: fixed-order reduce + 1/k! scaling (+ weight transpose) ----------------
__global__ __launch_bounds__(512) void moments_reduce(
    const float* __restrict__ part, float* __restrict__ mom, int nblk,
    const float* __restrict__ w1, const float* __restrict__ w2,
    float* __restrict__ wt)
{
    const int b = blockIdx.x;
    if (b < BB) {
        for (int i = threadIdx.x; i < MOM; i += 512) {
            float s = 0.f;
#pragma unroll 8
            for (int u = 0; u < nblk; ++u) s += part[(size_t)(b * nblk + u) * MOM + i];
            const int k = (i < KP) ? i : ((i - KP) >> 5);
            mom[b * MOM + i] = s * c_invf[k];
        }
    } else {
        for (int i = threadIdx.x; i < 3072; i += 512) {
            const int o = i / 96, cd = i % 96;
            wt[cd * 32 + o] = w1[i];
            wt[3072 + cd * 32 + o] = w2[i];
        }
    }
}

// ---------------- stage 3: fused x(Horner) -> conv1+relu -> conv2+res+relu ----------------
__global__ __launch_bounds__(256) void main_kernel(
    const float* __restrict__ inten, const float* __restrict__ mom,
    const float* __restrict__ wt, const float* __restrict__ b1,
    const float* __restrict__ b2, float* __restrict__ out)
{
    __shared__ float w1t[3072];     // [c*3+d][o]
    __shared__ float w2t[3072];
    __shared__ float b1s[EMB], b2s[EMB];
    __shared__ float xs[EMB][XSTR]; // x idx 0..131 (pos = start-2+idx)
    __shared__ float hs[EMB][XSTR]; // h idx i stored at [i-1]

    const int t = threadIdx.x;
    const int b = blockIdx.x / NT;
    const int tile = blockIdx.x % NT;
    const int start = tile * TOUT;
    const int e = t & 31;

    // per-thread Horner coefficients (pre-scaled by 1/k!)
    float Mreg[KP], Sreg[KP];
#pragma unroll
    for (int k = 0; k < KP; ++k) {
        Mreg[k] = mom[b * MOM + KP + k * EMB + e];
        Sreg[k] = mom[b * MOM + k];
    }

    // stage weights & biases (float4, coalesced)
    {
        const float4* src = (const float4*)wt;
        float4* d1 = (float4*)w1t;
        float4* d2 = (float4*)w2t;
        for (int i = t; i < 768; i += 256) { d1[i] = src[i]; d2[i] = src[768 + i]; }
        if (t < EMB) { b1s[t] = b1[t]; b2s[t] = b2[t]; }
    }
    __syncthreads();

    // ---- x-gen: xs[e][pos] = Horner_num(u)/Horner_den(u), zero outside [0,NPOS) ----
    for (int i = t; i < STG * EMB; i += 256) {
        const int pos = i >> 5;      // e == i&31 (stride 256 preserves lane)
        const int gp = start - 2 + pos;
        const bool valid = (gp >= 0) && (gp < NPOS);
        const float u = valid ? inten[b * NPOS + gp] * 0.01f : 0.f;
        float num = Mreg[KP - 1], den = Sreg[KP - 1];
#pragma unroll
        for (int k = KP - 2; k >= 0; --k) {
            num = fmaf(num, u, Mreg[k]);
            den = fmaf(den, u, Sreg[k]);
        }
        const float rd = valid ? __builtin_amdgcn_rcpf(den) : 0.f;
        xs[e][pos] = num * rd;
    }
    __syncthreads();

    const int g = t >> 5;
    const int o0 = g * 4;
    const int lane = t & 31;
    const int i0 = 4 * lane;

    // ---- conv1 + relu -> hs (h idx i0+1..i0+4 stored at i0..i0+3) ----
    {
        float a[4][4];
#pragma unroll
        for (int oo = 0; oo < 4; ++oo) {
            const float bv = b1s[o0 + oo];
#pragma unroll
            for (int p = 0; p < 4; ++p) a[oo][p] = bv;
        }
#pragma unroll 4
        for (int c = 0; c < 32; ++c) {
            const float4 xq = *(const float4*)&xs[c][i0];
            const float2 xr = *(const float2*)&xs[c][i0 + 4];
            const float xv[6] = {xq.x, xq.y, xq.z, xq.w, xr.x, xr.y};
            const float4 W0 = *(const float4*)&w1t[(c * 3 + 0) * 32 + o0];
            const float4 W1 = *(const float4*)&w1t[(c * 3 + 1) * 32 + o0];
            const float4 W2 = *(const float4*)&w1t[(c * 3 + 2) * 32 + o0];
            const float w0a[4] = {W0.x, W0.y, W0.z, W0.w};
            const float w1a[4] = {W1.x, W1.y, W1.z, W1.w};
            const float w2a[4] = {W2.x, W2.y, W2.z, W2.w};
#pragma unroll
            for (int oo = 0; oo < 4; ++oo)
#pragma unroll
                for (int p = 0; p < 4; ++p)
                    a[oo][p] = fmaf(w0a[oo], xv[p],
                               fmaf(w1a[oo], xv[p + 1],
                               fmaf(w2a[oo], xv[p + 2], a[oo][p])));
        }
#pragma unroll
        for (int oo = 0; oo < 4; ++oo) {
            float4 hv;
            float* hp = (float*)&hv;
#pragma unroll
            for (int p = 0; p < 4; ++p) {
                const int gp = start - 1 + i0 + p; // pos of h idx i0+1+p
                const bool vh = (gp >= 0) && (gp < NPOS);
                hp[p] = vh ? fmaxf(a[oo][p], 0.f) : 0.f;
            }
            *(float4*)&hs[o0 + oo][i0] = hv;
        }
    }
    __syncthreads();

    // ---- conv2 + residual + relu -> out (out idx i0+2..i0+5) ----
    {
        float a[4][4];
#pragma unroll
        for (int oo = 0; oo < 4; ++oo) {
            const float bv = b2s[o0 + oo];
#pragma unroll
            for (int p = 0; p < 4; ++p) a[oo][p] = bv;
        }
#pragma unroll 4
        for (int c = 0; c < 32; ++c) {
            const float4 hq = *(const float4*)&hs[c][i0];
            const float2 hr = *(const float2*)&hs[c][i0 + 4];
            const float hv[6] = {hq.x, hq.y, hq.z, hq.w, hr.x, hr.y};
            const float4 W0 = *(const float4*)&w2t[(c * 3 + 0) * 32 + o0];
            const float4 W1 = *(const float4*)&w2t[(c * 3 + 1) * 32 + o0];
            const float4 W2 = *(const float4*)&w2t[(c * 3 + 2) * 32 + o0];
            const float w0a[4] = {W0.x, W0.y, W0.z, W0.w};
            const float w1a[4] = {W1.x, W1.y, W1.z, W1.w};
            const float w2a[4] = {W2.x, W2.y, W2.z, W2.w};
#pragma unroll
            for (int oo = 0; oo < 4; ++oo)
#pragma unroll
                for (int p = 0; p < 4; ++p)
                    a[oo][p] = fmaf(w0a[oo], hv[p],
                               fmaf(w1a[oo], hv[p + 1],
                               fmaf(w2a[oo], hv[p + 2], a[oo][p])));
        }
        const int p0 = start + i0;                       // first output pos
        const int lim = min(start + TOUT, NPOS) - p0;    // #valid outputs
        if (lim > 0) {
#pragma unroll
            for (int oo = 0; oo < 4; ++oo) {
                const float2 x01 = *(const float2*)&xs[o0 + oo][i0 + 2];
                const float2 x23 = *(const float2*)&xs[o0 + oo][i0 + 4];
                float r[4];
                r[0] = fmaxf(x01.x + a[oo][0], 0.f);
                r[1] = fmaxf(x01.y + a[oo][1], 0.f);
                r[2] = fmaxf(x23.x + a[oo][2], 0.f);
                r[3] = fmaxf(x23.y + a[oo][3], 0.f);
                float* ob = out + (size_t)(b * EMB + o0 + oo) * NPOS + p0;
                if (lim >= 4) {
                    *(float4*)ob = make_float4(r[0], r[1], r[2], r[3]);
                } else {
#pragma unroll
                    for (int p = 0; p < 4; ++p)
                        if (p < lim) ob[p] = r[p];
                }
            }
        }
    }
}

extern "C" void kernel_launch(void* const* d_in, const int* in_sizes, int n_in,
                              void* d_out, int out_size, void* d_ws, size_t ws_size,
                              hipStream_t stream) {
    const float* inten = (const float*)d_in[0];
    const int* angle = (const int*)d_in[1];
    const float* emb = (const float*)d_in[2];
    const float* w1 = (const float*)d_in[3];
    const float* b1 = (const float*)d_in[4];
    const float* w2 = (const float*)d_in[5];
    const float* b2 = (const float*)d_in[6];
    float* out = (float*)d_out;

    float* mom = (float*)d_ws;                          // BB*528 floats  = 8448 B
    float* wt = (float*)((char*)d_ws + 8448);           // 6144 floats    = 24576 B
    float* part = (float*)((char*)d_ws + 8448 + 24576); // BB*nblk*528 floats

    int nblk = 128;
    while (nblk > 8 &&
           (size_t)(8448 + 24576) + (size_t)BB * nblk * MOM * 4 > ws_size)
        nblk >>= 1;
    const int jpb = (NPOS + nblk - 1) / nblk;
    const int jps = (jpb + 7) / 8;

    moments_partial<<<BB * nblk, 256, 0, stream>>>(inten, angle, emb, part, nblk, jpb, jps);
    moments_reduce<<<BB + 1, 512, 0, stream>>>(part, mom, nblk, w1, w2, wt);
    main_kernel<<<BB * NT, 256, 0, stream>>>(inten, mom, wt, b1, b2, out);
}

// Round 4
// 36.934 us; speedup vs baseline: 2.1900x; 1.0230x over previous
//
#include <hip/hip_runtime.h>

#define NPOS 8500
#define BB 4
#define EMB 32
#define KP 16
#define MOM 528            /* S[16] + M[16][32] coefficients per batch */
#define NBLK 32            /* j-chunks per batch in moments_partial */
#define TOUT 124           /* output positions per tile */
#define STG 132            /* staged x idx [0,132): pos start-2 .. start+129 */
#define STR 134            /* LDS row stride (floats): 8B-aligned rows, 2-way banks */
#define NT 69              /* ceil(8500/124) */

__device__ __constant__ float c_invf[KP] = {
    1.f, 1.f, 0.5f, 1.f/6.f, 1.f/24.f, 1.f/120.f, 1.f/720.f, 1.f/5040.f,
    1.f/40320.f, 1.f/362880.f, 1.f/3628800.f, 1.f/39916800.f,
    1.f/479001600.f, 1.f/6227020800.f, 1.f/87178291200.f, 1.f/1307674368000.f};

// ---------------- kernel 1: partial moments (fixed order) + weight transpose ----------------
// part layout: part[(b*MOM + i)*NBLK + blk]  (blk contiguous -> coalesced reduce)
__global__ __launch_bounds__(256) void moments_partial(
    const float* __restrict__ inten, const int* __restrict__ angle,
    const float* __restrict__ emb, float* __restrict__ part,
    const float* __restrict__ w1, const float* __restrict__ w2,
    float* __restrict__ wt)
{
    if (blockIdx.x == BB * NBLK) {
        // transpose [o][c*3+d] -> [c*3+d][o] once (scattered reads, done once GPU-wide)
        for (int i = threadIdx.x; i < 3072; i += 256) {
            wt[i] = w1[(i & 31) * 96 + (i >> 5)];
            wt[3072 + i] = w2[(i & 31) * 96 + (i >> 5)];
        }
        return;
    }
    const int b = blockIdx.x / NBLK;
    const int blk = blockIdx.x % NBLK;
    const int t = threadIdx.x;
    const int sub = t >> 5;   // 8 j-subchunks
    const int e = t & 31;     // embed lane
    const int jpb = (NPOS + NBLK - 1) / NBLK;   // 266
    const int jps = (jpb + 7) / 8;              // 34
    const int jlo = blk * jpb;
    const int jhi = min(jlo + jpb, NPOS);
    const int js = jlo + sub * jps;
    const int je = min(js + jps, jhi);

    float accM[KP], accS[KP];
#pragma unroll
    for (int k = 0; k < KP; ++k) { accM[k] = 0.f; accS[k] = 0.f; }

    const float* ib = inten + b * NPOS;
    const int* ab = angle + b * NPOS;
    for (int j = js; j < je; ++j) {
        const float v = ib[j] * 0.01f;
        const int a = ab[j];
        const float ev = emb[a * EMB + e];   // 128B row per 32-lane group
        float p = 1.0f;
        accM[0] += ev;
        accS[0] += 1.0f;
#pragma unroll
        for (int k = 1; k < KP; ++k) {
            p *= v;
            accM[k] = fmaf(p, ev, accM[k]);
            accS[k] += p;
        }
    }

    __shared__ float red[8][MOM];
#pragma unroll
    for (int k = 0; k < KP; ++k) red[sub][KP + k * EMB + e] = accM[k];
    if (e == 0) {
#pragma unroll
        for (int k = 0; k < KP; ++k) red[sub][k] = accS[k];
    }
    __syncthreads();
    for (int i = t; i < MOM; i += 256) {
        float s = 0.f;
#pragma unroll
        for (int u = 0; u < 8; ++u) s += red[u][i];
        part[((size_t)b * MOM + i) * NBLK + blk] = s;
    }
}

// ---------------- kernel 2: reduce + x(Horner) -> conv1+relu -> conv2+res+relu ----------------
__global__ __launch_bounds__(512, 4) void main_kernel(
    const float* __restrict__ inten, const float* __restrict__ part,
    const float* __restrict__ wt, const float* __restrict__ b1,
    const float* __restrict__ b2, float* __restrict__ out)
{
    __shared__ float w1t[3072];     // [c*3+d][o]
    __shared__ float w2t[3072];
    __shared__ float moms[MOM];
    __shared__ float b1s[EMB], b2s[EMB];
    __shared__ float xs[EMB][STR];  // x idx 0..131 (pos = start-2+idx)
    __shared__ float hs[EMB][STR];  // h idx j stored at [j-1]

    const int t = threadIdx.x;
    const int b = blockIdx.x / NT;
    const int tile = blockIdx.x % NT;
    const int start = tile * TOUT;
    const int e = t & 31;

    // stage weights (coalesced float4 from pre-transposed wt)
    {
        const float4* src = (const float4*)wt;
        float4* d1 = (float4*)w1t;
        float4* d2 = (float4*)w2t;
        for (int i = t; i < 768; i += 512) { d1[i] = src[i]; d2[i] = src[768 + i]; }
        if (t < EMB) { b1s[t] = b1[t]; b2s[t] = b2[t]; }
    }
    // reduce this batch's partials (sequential order -> deterministic) + 1/k!
    for (int i = t; i < MOM; i += 512) {
        const float* pr = &part[((size_t)b * MOM + i) * NBLK];
        float s = 0.f;
#pragma unroll
        for (int u = 0; u < NBLK; ++u) s += pr[u];
        const int k = (i < KP) ? i : ((i - KP) >> 5);
        moms[i] = s * c_invf[k];
    }
    __syncthreads();

    // per-thread Horner coefficients
    float Mreg[KP], Sreg[KP];
#pragma unroll
    for (int k = 0; k < KP; ++k) {
        Mreg[k] = moms[KP + k * EMB + e];
        Sreg[k] = moms[k];
    }

    // ---- x-gen: xs[e][pos] = Horner_num(u)/Horner_den(u), zero outside [0,NPOS) ----
    for (int i = t; i < STG * EMB; i += 512) {
        const int pos = i >> 5;      // e == i&31 (stride 512 preserves lane)
        const int gp = start - 2 + pos;
        const bool valid = (gp >= 0) && (gp < NPOS);
        const float u = valid ? inten[b * NPOS + gp] * 0.01f : 0.f;
        float num = Mreg[KP - 1], den = Sreg[KP - 1];
#pragma unroll
        for (int k = KP - 2; k >= 0; --k) {
            num = fmaf(num, u, Mreg[k]);
            den = fmaf(den, u, Sreg[k]);
        }
        const float rd = valid ? __builtin_amdgcn_rcpf(den) : 0.f;
        xs[e][pos] = num * rd;
    }
    __syncthreads();

    const int g = t >> 6;        // 8 channel groups of 4 channels
    const int o0 = g * 4;
    const int lane = t & 63;     // 64 position lanes, 2 positions each
    const int i0 = 2 * lane;

    // ---- conv1 + relu -> hs (h idx i0+1, i0+2 stored at i0, i0+1) ----
    {
        float a[4][2];
#pragma unroll
        for (int oo = 0; oo < 4; ++oo) { a[oo][0] = b1s[o0 + oo]; a[oo][1] = b1s[o0 + oo]; }
#pragma unroll 4
        for (int c = 0; c < 32; ++c) {
            const float2 xa = *(const float2*)&xs[c][i0];
            const float2 xb = *(const float2*)&xs[c][i0 + 2];
            const float xv[4] = {xa.x, xa.y, xb.x, xb.y};
            const float4 W0 = *(const float4*)&w1t[(c * 3 + 0) * 32 + o0];
            const float4 W1 = *(const float4*)&w1t[(c * 3 + 1) * 32 + o0];
            const float4 W2 = *(const float4*)&w1t[(c * 3 + 2) * 32 + o0];
            const float w0a[4] = {W0.x, W0.y, W0.z, W0.w};
            const float w1a[4] = {W1.x, W1.y, W1.z, W1.w};
            const float w2a[4] = {W2.x, W2.y, W2.z, W2.w};
#pragma unroll
            for (int oo = 0; oo < 4; ++oo) {
                a[oo][0] = fmaf(w0a[oo], xv[0],
                           fmaf(w1a[oo], xv[1],
                           fmaf(w2a[oo], xv[2], a[oo][0])));
                a[oo][1] = fmaf(w0a[oo], xv[1],
                           fmaf(w1a[oo], xv[2],
                           fmaf(w2a[oo], xv[3], a[oo][1])));
            }
        }
        const int gp0 = start - 1 + i0;     // pos of h idx i0+1
        const bool v0 = (gp0 >= 0) && (gp0 < NPOS);
        const bool v1 = (gp0 + 1 >= 0) && (gp0 + 1 < NPOS);
#pragma unroll
        for (int oo = 0; oo < 4; ++oo) {
            float2 hv;
            hv.x = v0 ? fmaxf(a[oo][0], 0.f) : 0.f;
            hv.y = v1 ? fmaxf(a[oo][1], 0.f) : 0.f;
            *(float2*)&hs[o0 + oo][i0] = hv;
        }
    }
    __syncthreads();

    // ---- conv2 + residual + relu -> out (out idx i0+2, i0+3) ----
    {
        float a[4][2];
#pragma unroll
        for (int oo = 0; oo < 4; ++oo) { a[oo][0] = b2s[o0 + oo]; a[oo][1] = b2s[o0 + oo]; }
#pragma unroll 4
        for (int c = 0; c < 32; ++c) {
            const float2 ha = *(const float2*)&hs[c][i0];
            const float2 hb = *(const float2*)&hs[c][i0 + 2];
            const float hv[4] = {ha.x, ha.y, hb.x, hb.y};
            const float4 W0 = *(const float4*)&w2t[(c * 3 + 0) * 32 + o0];
            const float4 W1 = *(const float4*)&w2t[(c * 3 + 1) * 32 + o0];
            const float4 W2 = *(const float4*)&w2t[(c * 3 + 2) * 32 + o0];
            const float w0a[4] = {W0.x, W0.y, W0.z, W0.w};
            const float w1a[4] = {W1.x, W1.y, W1.z, W1.w};
            const float w2a[4] = {W2.x, W2.y, W2.z, W2.w};
#pragma unroll
            for (int oo = 0; oo < 4; ++oo) {
                a[oo][0] = fmaf(w0a[oo], hv[0],
                           fmaf(w1a[oo], hv[1],
                           fmaf(w2a[oo], hv[2], a[oo][0])));
                a[oo][1] = fmaf(w0a[oo], hv[1],
                           fmaf(w1a[oo], hv[2],
                           fmaf(w2a[oo], hv[3], a[oo][1])));
            }
        }
        // outputs at tile idx i0+2, i0+3 -> positions start+i0, start+i0+1
        const int p0 = start + i0;
        if (i0 < TOUT && p0 < NPOS) {
            const bool full = (i0 + 1 < TOUT) && (p0 + 1 < NPOS);
#pragma unroll
            for (int oo = 0; oo < 4; ++oo) {
                const float2 xr = *(const float2*)&xs[o0 + oo][i0 + 2];
                const float r0 = fmaxf(xr.x + a[oo][0], 0.f);
                const float r1 = fmaxf(xr.y + a[oo][1], 0.f);
                float* ob = out + (size_t)(b * EMB + o0 + oo) * NPOS + p0;
                if (full) *(float2*)ob = make_float2(r0, r1);
                else ob[0] = r0;
            }
        }
    }
}

extern "C" void kernel_launch(void* const* d_in, const int* in_sizes, int n_in,
                              void* d_out, int out_size, void* d_ws, size_t ws_size,
                              hipStream_t stream) {
    const float* inten = (const float*)d_in[0];
    const int* angle = (const int*)d_in[1];
    const float* emb = (const float*)d_in[2];
    const float* w1 = (const float*)d_in[3];
    const float* b1 = (const float*)d_in[4];
    const float* w2 = (const float*)d_in[5];
    const float* b2 = (const float*)d_in[6];
    float* out = (float*)d_out;

    float* part = (float*)d_ws;                           // BB*528*32 floats = 270336 B
    float* wt = (float*)((char*)d_ws + (size_t)BB * MOM * NBLK * 4); // 6144 floats

    moments_partial<<<BB * NBLK + 1, 256, 0, stream>>>(inten, angle, emb, part, w1, w2, wt);
    main_kernel<<<BB * NT, 512, 0, stream>>>(inten, part, wt, b1, b2, out);
}

// Round 5
// 30.027 us; speedup vs baseline: 2.6938x; 1.2300x over previous
//
#include <hip/hip_runtime.h>

#define NPOS 8500
#define BB 4
#define EMB 32
#define KP 16
#define MOM 528            /* S[16] + M[16][32] coefficients per batch */
#define NBLK 64            /* j-chunks per batch in moments_partial */
#define TOUT 133           /* output positions per tile; 64*133 = 8512 */
#define NT 64              /* tiles per batch -> grid = 256 exactly */
#define STG 138            /* staged x idx [0,138): pos start-2 .. start+135 */
#define STR 142            /* LDS row stride (floats): 8B-aligned, 2-way banks */
#define THR 576            /* 9 waves: 8 ch-groups x 72 position lanes */

__device__ __constant__ float c_invf[KP] = {
    1.f, 1.f, 0.5f, 1.f/6.f, 1.f/24.f, 1.f/120.f, 1.f/720.f, 1.f/5040.f,
    1.f/40320.f, 1.f/362880.f, 1.f/3628800.f, 1.f/39916800.f,
    1.f/479001600.f, 1.f/6227020800.f, 1.f/87178291200.f, 1.f/1307674368000.f};

// ---------------- kernel 1: partial moments (fixed order) + weight transpose ----------------
// part layout: part[(b*MOM + i)*NBLK + blk]  (blk contiguous -> float4 reduce)
__global__ __launch_bounds__(256) void moments_partial(
    const float* __restrict__ inten, const int* __restrict__ angle,
    const float* __restrict__ emb, float* __restrict__ part,
    const float* __restrict__ w1, const float* __restrict__ w2,
    float* __restrict__ wt)
{
    if (blockIdx.x == BB * NBLK) {
        for (int i = threadIdx.x; i < 3072; i += 256) {
            wt[i] = w1[(i & 31) * 96 + (i >> 5)];
            wt[3072 + i] = w2[(i & 31) * 96 + (i >> 5)];
        }
        return;
    }
    const int b = blockIdx.x >> 6;
    const int blk = blockIdx.x & 63;
    const int t = threadIdx.x;
    const int sub = t >> 5;                     // 8 j-subchunks
    const int e = t & 31;                       // embed lane
    const int jpb = (NPOS + NBLK - 1) / NBLK;   // 133
    const int jps = (jpb + 7) / 8;              // 17
    const int jlo = blk * jpb;
    const int jhi = min(jlo + jpb, NPOS);
    const int js = jlo + sub * jps;
    const int je = min(js + jps, jhi);

    float accM[KP], accS[KP];
#pragma unroll
    for (int k = 0; k < KP; ++k) { accM[k] = 0.f; accS[k] = 0.f; }

    const float* ib = inten + b * NPOS;
    const int* ab = angle + b * NPOS;
    for (int j = js; j < je; ++j) {
        const float v = ib[j] * 0.01f;
        const int a = ab[j];
        const float ev = emb[a * EMB + e];      // 128B row per 32-lane group
        float p = 1.0f;
        accM[0] += ev;
        accS[0] += 1.0f;
#pragma unroll
        for (int k = 1; k < KP; ++k) {
            p *= v;
            accM[k] = fmaf(p, ev, accM[k]);
            accS[k] += p;
        }
    }

    __shared__ float red[8][MOM];
#pragma unroll
    for (int k = 0; k < KP; ++k) red[sub][KP + k * EMB + e] = accM[k];
    if (e == 0) {
#pragma unroll
        for (int k = 0; k < KP; ++k) red[sub][k] = accS[k];
    }
    __syncthreads();
    for (int i = t; i < MOM; i += 256) {
        float s = 0.f;
#pragma unroll
        for (int u = 0; u < 8; ++u) s += red[u][i];
        part[((size_t)b * MOM + i) * NBLK + blk] = s;
    }
}

// ---------------- kernel 2: reduce + x(Horner) -> conv1+relu -> conv2+res+relu ----------------
__global__ __launch_bounds__(THR) void main_kernel(
    const float* __restrict__ inten, const float* __restrict__ part,
    const float* __restrict__ wt, const float* __restrict__ b1,
    const float* __restrict__ b2, float* __restrict__ out)
{
    __shared__ float w1t[3072];     // [c*3+d][o]
    __shared__ float w2t[3072];
    __shared__ float moms[MOM];
    __shared__ float b1s[EMB], b2s[EMB];
    __shared__ float xs[EMB][STR];  // x idx 0..137 (pos = start-2+idx)
    __shared__ float hs[EMB][STR];  // h idx j stored at [j-1]

    const int t = threadIdx.x;
    const int b = blockIdx.x >> 6;      // NT = 64
    const int tile = blockIdx.x & 63;
    const int start = tile * TOUT;
    const int e = t & 31;

    // stage weights (coalesced float4 from pre-transposed wt)
    {
        const float4* src = (const float4*)wt;
        float4* d1 = (float4*)w1t;
        float4* d2 = (float4*)w2t;
        for (int i = t; i < 768; i += THR) { d1[i] = src[i]; d2[i] = src[768 + i]; }
        if (t < EMB) { b1s[t] = b1[t]; b2s[t] = b2[t]; }
    }
    // reduce this batch's partials: one coeff per thread, 16 x float4, 4-way ILP
    if (t < MOM) {
        const float4* pr = (const float4*)&part[((size_t)b * MOM + t) * NBLK];
        float4 a0 = pr[0], a1 = pr[1], a2 = pr[2], a3 = pr[3];
#pragma unroll
        for (int u = 4; u < 16; u += 4) {
            const float4 v0 = pr[u], v1 = pr[u + 1], v2 = pr[u + 2], v3 = pr[u + 3];
            a0.x += v0.x; a0.y += v0.y; a0.z += v0.z; a0.w += v0.w;
            a1.x += v1.x; a1.y += v1.y; a1.z += v1.z; a1.w += v1.w;
            a2.x += v2.x; a2.y += v2.y; a2.z += v2.z; a2.w += v2.w;
            a3.x += v3.x; a3.y += v3.y; a3.z += v3.z; a3.w += v3.w;
        }
        const float s = ((a0.x + a0.y) + (a0.z + a0.w)) + ((a1.x + a1.y) + (a1.z + a1.w))
                      + ((a2.x + a2.y) + (a2.z + a2.w)) + ((a3.x + a3.y) + (a3.z + a3.w));
        const int k = (t < KP) ? t : ((t - KP) >> 5);
        moms[t] = s * c_invf[k];
    }
    __syncthreads();

    // per-thread Horner coefficients (pre-scaled by 1/k!)
    float Mreg[KP], Sreg[KP];
#pragma unroll
    for (int k = 0; k < KP; ++k) {
        Mreg[k] = moms[KP + k * EMB + e];
        Sreg[k] = moms[k];
    }

    // ---- x-gen: xs[e][pos] = Horner_num(u)/Horner_den(u), zero outside [0,NPOS) ----
    for (int i = t; i < STG * EMB; i += THR) {   // THR % 32 == 0 -> lane e preserved
        const int pos = i >> 5;
        const int gp = start - 2 + pos;
        const bool valid = (gp >= 0) && (gp < NPOS);
        const float u = valid ? inten[b * NPOS + gp] * 0.01f : 0.f;
        float num = Mreg[KP - 1], den = Sreg[KP - 1];
#pragma unroll
        for (int k = KP - 2; k >= 0; --k) {
            num = fmaf(num, u, Mreg[k]);
            den = fmaf(den, u, Sreg[k]);
        }
        const float rd = valid ? __builtin_amdgcn_rcpf(den) : 0.f;
        xs[e][pos] = num * rd;
    }
    __syncthreads();

    const int g = t / 72;        // channel group (4 channels)
    const int lane = t - g * 72; // position lane (2 positions)
    const int o0 = g * 4;
    const int i0 = 2 * lane;

    // ---- conv1 + relu -> hs (h idx i0+1, i0+2 stored at i0, i0+1); need h 1..136 ----
    if (lane < 68) {
        float a[4][2];
#pragma unroll
        for (int oo = 0; oo < 4; ++oo) { a[oo][0] = b1s[o0 + oo]; a[oo][1] = b1s[o0 + oo]; }
#pragma unroll 4
        for (int c = 0; c < 32; ++c) {
            const float2 xa = *(const float2*)&xs[c][i0];
            const float2 xb = *(const float2*)&xs[c][i0 + 2];
            const float xv[4] = {xa.x, xa.y, xb.x, xb.y};
            const float4 W0 = *(const float4*)&w1t[(c * 3 + 0) * 32 + o0];
            const float4 W1 = *(const float4*)&w1t[(c * 3 + 1) * 32 + o0];
            const float4 W2 = *(const float4*)&w1t[(c * 3 + 2) * 32 + o0];
            const float w0a[4] = {W0.x, W0.y, W0.z, W0.w};
            const float w1a[4] = {W1.x, W1.y, W1.z, W1.w};
            const float w2a[4] = {W2.x, W2.y, W2.z, W2.w};
#pragma unroll
            for (int oo = 0; oo < 4; ++oo) {
                a[oo][0] = fmaf(w0a[oo], xv[0],
                           fmaf(w1a[oo], xv[1],
                           fmaf(w2a[oo], xv[2], a[oo][0])));
                a[oo][1] = fmaf(w0a[oo], xv[1],
                           fmaf(w1a[oo], xv[2],
                           fmaf(w2a[oo], xv[3], a[oo][1])));
            }
        }
        const int gp0 = start - 1 + i0;   // pos of h idx i0+1
        const bool v0 = (gp0 >= 0) && (gp0 < NPOS);
        const bool v1 = (gp0 + 1 >= 0) && (gp0 + 1 < NPOS);
#pragma unroll
        for (int oo = 0; oo < 4; ++oo) {
            float2 hv;
            hv.x = v0 ? fmaxf(a[oo][0], 0.f) : 0.f;
            hv.y = v1 ? fmaxf(a[oo][1], 0.f) : 0.f;
            *(float2*)&hs[o0 + oo][i0] = hv;
        }
    }
    __syncthreads();

    // ---- conv2 + residual + relu -> out (out idx i0+2, i0+3 -> pos start+i0, +1) ----
    if (lane < 67) {
        float a[4][2];
#pragma unroll
        for (int oo = 0; oo < 4; ++oo) { a[oo][0] = b2s[o0 + oo]; a[oo][1] = b2s[o0 + oo]; }
#pragma unroll 4
        for (int c = 0; c < 32; ++c) {
            const float2 ha = *(const float2*)&hs[c][i0];
            const float2 hb = *(const float2*)&hs[c][i0 + 2];
            const float hv[4] = {ha.x, ha.y, hb.x, hb.y};
            const float4 W0 = *(const float4*)&w2t[(c * 3 + 0) * 32 + o0];
            const float4 W1 = *(const float4*)&w2t[(c * 3 + 1) * 32 + o0];
            const float4 W2 = *(const float4*)&w2t[(c * 3 + 2) * 32 + o0];
            const float w0a[4] = {W0.x, W0.y, W0.z, W0.w};
            const float w1a[4] = {W1.x, W1.y, W1.z, W1.w};
            const float w2a[4] = {W2.x, W2.y, W2.z, W2.w};
#pragma unroll
            for (int oo = 0; oo < 4; ++oo) {
                a[oo][0] = fmaf(w0a[oo], hv[0],
                           fmaf(w1a[oo], hv[1],
                           fmaf(w2a[oo], hv[2], a[oo][0])));
                a[oo][1] = fmaf(w0a[oo], hv[1],
                           fmaf(w1a[oo], hv[2],
                           fmaf(w2a[oo], hv[3], a[oo][1])));
            }
        }
        const int p0 = start + i0;
        if (i0 < TOUT && p0 < NPOS) {
            const bool full = (i0 + 1 < TOUT) && (p0 + 1 < NPOS);
#pragma unroll
            for (int oo = 0; oo < 4; ++oo) {
                const float2 xr = *(const float2*)&xs[o0 + oo][i0 + 2];
                const float r0 = fmaxf(xr.x + a[oo][0], 0.f);
                const float r1 = fmaxf(xr.y + a[oo][1], 0.f);
                float* ob = out + (size_t)(b * EMB + o0 + oo) * NPOS + p0;
                if (full) *(float2*)ob = make_float2(r0, r1);
                else ob[0] = r0;
            }
        }
    }
}

extern "C" void kernel_launch(void* const* d_in, const int* in_sizes, int n_in,
                              void* d_out, int out_size, void* d_ws, size_t ws_size,
                              hipStream_t stream) {
    const float* inten = (const float*)d_in[0];
    const int* angle = (const int*)d_in[1];
    const float* emb = (const float*)d_in[2];
    const float* w1 = (const float*)d_in[3];
    const float* b1 = (const float*)d_in[4];
    const float* w2 = (const float*)d_in[5];
    const float* b2 = (const float*)d_in[6];
    float* out = (float*)d_out;

    float* part = (float*)d_ws;                                      // BB*528*64*4 = 540672 B
    float* wt = (float*)((char*)d_ws + (size_t)BB * MOM * NBLK * 4); // 6144 floats

    moments_partial<<<BB * NBLK + 1, 256, 0, stream>>>(inten, angle, emb, part, w1, w2, wt);
    main_kernel<<<BB * NT, THR, 0, stream>>>(inten, part, wt, b1, b2, out);
}